// Round 1
// baseline (116.412 us; speedup 1.0000x reference)
//
#include <hip/hip_runtime.h>

// out[b,o] = sum_i silu(x)*BW + ((xs^2-1)*exp(-xs^2/2))*WW + bias,  xs=(x-T)/S
// ROUND 7: register tile 4x4 -> 8x4 (BT 64->128). Theory: inner loop was LDS
// read-BW bound (28 ds_read_b128 per 850 VALU-cyc = ~135 B/cyc/CU demand vs
// ~128 capacity -> VALUBusy capped at 62%). Bytes/contribution = 20/R + 8/C:
// R=4,C=4 -> 7B; R=8,C=4 -> 4.5B, dropping LDS demand to ~87 B/cyc so the
// VALU (1 exp2 + 2.5 pk-ops/element, irreducible) becomes the limiter.
// Inner math identical to the verified round-2/6 kernel:
//   a2 = C2/s^2, m1 = -2*a2*t, m2' = a2*t^2 - C2, q = w * 2^C2 / C2
//   p = a2*x^2 + m1*x + m2';  contribution = p * q * 2^p
// with C2 = -0.5*log2(e).

constexpr int IN_F  = 512;
constexpr int OUT_F = 512;
constexpr int BATCH = 1024;
constexpr int BT = 128, OT = 64;    // block tile (BT doubled this round)
constexpr int KS = 8;               // k-split -> grid 8x8x8 = 512 blocks
constexpr int KR = IN_F / KS;       // 64 k per block
constexpr int IT = 16;              // k chunk in LDS
constexpr int PITCH = IT + 4;       // 16B-aligned rows, worst 2-way banks (free)
constexpr int NCH = KR / IT;        // 4 chunks
constexpr int BO  = BATCH * OUT_F;  // 524288

#define LOG2E 1.44269504088897f
#define C2f   (-0.72134752044448f)
#define NC2f  ( 0.72134752044448f)
#define RQf   (-0.84083003f)   /* 2^C2 / C2 = e^{-1/2}/C2 */

typedef float v2f __attribute__((ext_vector_type(2)));

__device__ __forceinline__ float fexp2(float v) { return __builtin_amdgcn_exp2f(v); }
__device__ __forceinline__ float frcp(float v)  { return __builtin_amdgcn_rcpf(v); }
__device__ __forceinline__ v2f pkfma(v2f a, v2f b, v2f c) {
  return __builtin_elementwise_fma(a, b, c);
}
__device__ __forceinline__ float fsilu(float v) {
  return v * frcp(1.f + fexp2(v * -LOG2E));
}

__global__ __launch_bounds__(256, 2)
void wkan_main(const float* __restrict__ x, const float* __restrict__ basew,
               const float* __restrict__ wavew, const float* __restrict__ scale,
               const float* __restrict__ transl, const float* __restrict__ bias,
               float* __restrict__ partial, float* __restrict__ out, int use_ws)
{
  __shared__ float lx [BT * PITCH];   // 10240 B
  __shared__ float lsx[BT * PITCH];   // 10240 B
  __shared__ float la [OT * PITCH];   // 5120 B each
  __shared__ float lm [OT * PITCH];
  __shared__ float ln [OT * PITCH];
  __shared__ float lq [OT * PITCH];
  __shared__ float lb [OT * PITCH];   // total 46080 B

  const int tid = threadIdx.x;
  const int b0 = blockIdx.x * BT;
  const int o0 = blockIdx.y * OT;
  const int ks = blockIdx.z;
  const int k0 = ks * KR;

  const int srow = tid >> 2;        // 0..63 staging row
  const int sc4  = (tid & 3) * 4;   // 0,4,8,12
  const int lofs = srow * PITCH + sc4;

  const int to = tid & 15;          // output col group (cols to + 16c)
  const int tb = tid >> 4;          // output row group 0..15 (rows tb + 16r)

  v2f zz; zz.x = 0.f; zz.y = 0.f;
  v2f acc[8][4];
#pragma unroll
  for (int r = 0; r < 8; ++r)
#pragma unroll
    for (int c = 0; c < 4; ++c) acc[r][c] = zz;

  for (int kc = 0; kc < NCH; ++kc) {
    const int g = k0 + kc * IT + sc4;
    __syncthreads();
    // ---------- stage chunk ----------
    {
      // x: 128 rows, each thread stages rows srow and srow+64
      float4 xv0 = *(const float4*)(x + (size_t)(b0 + srow) * IN_F + g);
      float4 xv1 = *(const float4*)(x + (size_t)(b0 + srow + 64) * IN_F + g);
      float4 sx0, sx1;
      sx0.x = fsilu(xv0.x); sx0.y = fsilu(xv0.y); sx0.z = fsilu(xv0.z); sx0.w = fsilu(xv0.w);
      sx1.x = fsilu(xv1.x); sx1.y = fsilu(xv1.y); sx1.z = fsilu(xv1.z); sx1.w = fsilu(xv1.w);
      *(float4*)(lx  + lofs) = xv0;
      *(float4*)(lsx + lofs) = sx0;
      *(float4*)(lx  + lofs + 64 * PITCH) = xv1;
      *(float4*)(lsx + lofs + 64 * PITCH) = sx1;

      // params: 64 rows, one float4 per array per thread
      float4 sv = *(const float4*)(scale  + (size_t)(o0 + srow) * IN_F + g);
      float4 tv = *(const float4*)(transl + (size_t)(o0 + srow) * IN_F + g);
      float4 av, mv, nv;
      {
        float a2, a2t;
        a2 = C2f * frcp(sv.x * sv.x); a2t = a2 * tv.x;
        av.x = a2; mv.x = -2.f * a2t; nv.x = fmaf(a2t, tv.x, NC2f);
        a2 = C2f * frcp(sv.y * sv.y); a2t = a2 * tv.y;
        av.y = a2; mv.y = -2.f * a2t; nv.y = fmaf(a2t, tv.y, NC2f);
        a2 = C2f * frcp(sv.z * sv.z); a2t = a2 * tv.z;
        av.z = a2; mv.z = -2.f * a2t; nv.z = fmaf(a2t, tv.z, NC2f);
        a2 = C2f * frcp(sv.w * sv.w); a2t = a2 * tv.w;
        av.w = a2; mv.w = -2.f * a2t; nv.w = fmaf(a2t, tv.w, NC2f);
      }
      *(float4*)(la + lofs) = av;
      *(float4*)(lm + lofs) = mv;
      *(float4*)(ln + lofs) = nv;

      float4 wv = *(const float4*)(wavew + (size_t)(o0 + srow) * IN_F + g);
      float4 qv;
      qv.x = wv.x * RQf; qv.y = wv.y * RQf; qv.z = wv.z * RQf; qv.w = wv.w * RQf;
      *(float4*)(lq + lofs) = qv;

      float4 bv = *(const float4*)(basew + (size_t)(o0 + srow) * IN_F + g);
      *(float4*)(lb + lofs) = bv;
    }
    __syncthreads();

    // ---------- compute: 8x4 outputs/thread ----------
    for (int ii = 0; ii < IT; ii += 4) {
      float4 xr[8], sr[8], x2[8];
#pragma unroll
      for (int r = 0; r < 8; ++r) {
        const int row = (tb + 16 * r) * PITCH + ii;
        xr[r] = *(const float4*)(lx + row);
        sr[r] = *(const float4*)(lsx + row);
        x2[r].x = xr[r].x * xr[r].x;
        x2[r].y = xr[r].y * xr[r].y;
        x2[r].z = xr[r].z * xr[r].z;
        x2[r].w = xr[r].w * xr[r].w;
      }
#pragma unroll
      for (int c = 0; c < 4; ++c) {
        const int orow = (to + 16 * c) * PITCH + ii;
        float4 A = *(const float4*)(la + orow);
        float4 M = *(const float4*)(lm + orow);
        float4 N = *(const float4*)(ln + orow);
        float4 Q = *(const float4*)(lq + orow);
        float4 B = *(const float4*)(lb + orow);
        v2f Al = {A.x, A.y}, Ah = {A.z, A.w};
        v2f Ml = {M.x, M.y}, Mh = {M.z, M.w};
        v2f Nl = {N.x, N.y}, Nh = {N.z, N.w};
        v2f Ql = {Q.x, Q.y}, Qh = {Q.z, Q.w};
        v2f Bl = {B.x, B.y}, Bh = {B.z, B.w};
#pragma unroll
        for (int r = 0; r < 8; ++r) {
          v2f xl  = {xr[r].x, xr[r].y}, xh  = {xr[r].z, xr[r].w};
          v2f x2l = {x2[r].x, x2[r].y}, x2h = {x2[r].z, x2[r].w};
          v2f sl  = {sr[r].x, sr[r].y}, sh  = {sr[r].z, sr[r].w};
          v2f p, e, gg;
          p = pkfma(Al, x2l, pkfma(Ml, xl, Nl));
          e.x = fexp2(p.x); e.y = fexp2(p.y);
          gg = p * Ql;
          acc[r][c] = pkfma(gg, e, acc[r][c]);
          acc[r][c] = pkfma(sl, Bl, acc[r][c]);
          p = pkfma(Ah, x2h, pkfma(Mh, xh, Nh));
          e.x = fexp2(p.x); e.y = fexp2(p.y);
          gg = p * Qh;
          acc[r][c] = pkfma(gg, e, acc[r][c]);
          acc[r][c] = pkfma(sh, Bh, acc[r][c]);
        }
      }
    }
  }

  // ---------- epilogue ----------
#pragma unroll
  for (int r = 0; r < 8; ++r) {
    const int br = b0 + tb + 16 * r;
#pragma unroll
    for (int c = 0; c < 4; ++c) {
      const int oc = o0 + to + 16 * c;
      float res = acc[r][c].x + acc[r][c].y;
      if (use_ws) {
        partial[(size_t)ks * BO + (size_t)br * OUT_F + oc] = res;
      } else {
        if (ks == 0) res += bias[oc];
        atomicAdd(out + (size_t)br * OUT_F + oc, res);
      }
    }
  }
}

__global__ __launch_bounds__(256)
void wkan_reduce(const float* __restrict__ partial, const float* __restrict__ bias,
                 float* __restrict__ out)
{
  const int i4 = (blockIdx.x * 256 + threadIdx.x) * 4;
  float4 r = *(const float4*)(bias + (i4 & (OUT_F - 1)));
#pragma unroll
  for (int k = 0; k < KS; ++k) {
    float4 a = *(const float4*)(partial + (size_t)k * BO + i4);
    r.x += a.x; r.y += a.y; r.z += a.z; r.w += a.w;
  }
  *(float4*)(out + i4) = r;
}

extern "C" void kernel_launch(void* const* d_in, const int* in_sizes, int n_in,
                              void* d_out, int out_size, void* d_ws, size_t ws_size,
                              hipStream_t stream) {
  const float* x  = (const float*)d_in[0];
  const float* bw = (const float*)d_in[1];
  const float* ww = (const float*)d_in[2];
  const float* sc = (const float*)d_in[3];
  const float* tr = (const float*)d_in[4];
  const float* bi = (const float*)d_in[5];
  float* out = (float*)d_out;

  const int use_ws = ws_size >= (size_t)KS * BO * sizeof(float) ? 1 : 0;
  if (!use_ws) {
    hipMemsetAsync(d_out, 0, (size_t)out_size * sizeof(float), stream);
  }
  dim3 grid(BATCH / BT, OUT_F / OT, KS);  // 8 x 8 x 8 = 512 blocks, 2/CU
  wkan_main<<<grid, dim3(256), 0, stream>>>(x, bw, ww, sc, tr, bi,
                                            (float*)d_ws, out, use_ws);
  if (use_ws) {
    wkan_reduce<<<dim3(BO / 1024), dim3(256), 0, stream>>>((const float*)d_ws, bi, out);
  }
}

// Round 2
// 114.832 us; speedup vs baseline: 1.0138x; 1.0138x over previous
//
#include <hip/hip_runtime.h>

// out[b,o] = sum_i silu(x)*BW + ((xs^2-1)*exp(-xs^2/2))*WW + bias,  xs=(x-T)/S
// ROUND 8: round-7 tile (BT=128, 8x4/thread) + T14 async-STAGE split.
// Round-7 post-mortem: LDS pipe time dropped as predicted (~36->~23us) but
// dur rose 54->57.5us; occupancy 16% (grid 512 = 2 blocks/CU) left the
// per-chunk staging phase (global L2 latency + transform + LDS write) fully
// serialized behind barriers ~8x per block. Fix: issue chunk t+1's global
// loads into registers right after compute of chunk t begins (latency hides
// under ~4 ii-steps of VALU); transform+LDS-write at top of next iteration.
// Inner math identical to the verified round-2 kernel:
//   a2 = C2/s^2, m1 = -2*a2*t, m2' = a2*t^2 - C2, q = w * 2^C2 / C2
//   p = a2*x^2 + m1*x + m2';  contribution = p * q * 2^p,  C2 = -0.5*log2(e)

constexpr int IN_F  = 512;
constexpr int OUT_F = 512;
constexpr int BATCH = 1024;
constexpr int BT = 128, OT = 64;    // block tile
constexpr int KS = 8;               // k-split -> grid 8x8x8 = 512 blocks
constexpr int KR = IN_F / KS;       // 64 k per block
constexpr int IT = 16;              // k chunk in LDS
constexpr int PITCH = IT + 4;       // 16B-aligned rows, worst 2-way banks (free)
constexpr int NCH = KR / IT;        // 4 chunks
constexpr int BO  = BATCH * OUT_F;  // 524288

#define LOG2E 1.44269504088897f
#define C2f   (-0.72134752044448f)
#define NC2f  ( 0.72134752044448f)
#define RQf   (-0.84083003f)   /* 2^C2 / C2 = e^{-1/2}/C2 */

typedef float v2f __attribute__((ext_vector_type(2)));

__device__ __forceinline__ float fexp2(float v) { return __builtin_amdgcn_exp2f(v); }
__device__ __forceinline__ float frcp(float v)  { return __builtin_amdgcn_rcpf(v); }
__device__ __forceinline__ v2f pkfma(v2f a, v2f b, v2f c) {
  return __builtin_elementwise_fma(a, b, c);
}
__device__ __forceinline__ float fsilu(float v) {
  return v * frcp(1.f + fexp2(v * -LOG2E));
}

__global__ __launch_bounds__(256, 2)
void wkan_main(const float* __restrict__ x, const float* __restrict__ basew,
               const float* __restrict__ wavew, const float* __restrict__ scale,
               const float* __restrict__ transl, const float* __restrict__ bias,
               float* __restrict__ partial, float* __restrict__ out, int use_ws)
{
  __shared__ float lx [BT * PITCH];   // 10240 B
  __shared__ float lsx[BT * PITCH];   // 10240 B
  __shared__ float la [OT * PITCH];   // 5120 B each
  __shared__ float lm [OT * PITCH];
  __shared__ float ln [OT * PITCH];
  __shared__ float lq [OT * PITCH];
  __shared__ float lb [OT * PITCH];   // total 46080 B

  const int tid = threadIdx.x;
  const int b0 = blockIdx.x * BT;
  const int o0 = blockIdx.y * OT;
  const int ks = blockIdx.z;
  const int k0 = ks * KR;

  const int srow = tid >> 2;        // 0..63 staging row
  const int sc4  = (tid & 3) * 4;   // 0,4,8,12
  const int lofs = srow * PITCH + sc4;

  const int to = tid & 15;          // output col group (cols to + 16c)
  const int tb = tid >> 4;          // output row group 0..15 (rows tb + 16r)

  v2f zz; zz.x = 0.f; zz.y = 0.f;
  v2f acc[8][4];
#pragma unroll
  for (int r = 0; r < 8; ++r)
#pragma unroll
    for (int c = 0; c < 4; ++c) acc[r][c] = zz;

  // prefetch registers (live across the compute phase)
  float4 xv0, xv1, sv, tv, wv, bv;

  {
    const int g = k0 + sc4;
    xv0 = *(const float4*)(x      + (size_t)(b0 + srow)      * IN_F + g);
    xv1 = *(const float4*)(x      + (size_t)(b0 + srow + 64) * IN_F + g);
    sv  = *(const float4*)(scale  + (size_t)(o0 + srow) * IN_F + g);
    tv  = *(const float4*)(transl + (size_t)(o0 + srow) * IN_F + g);
    wv  = *(const float4*)(wavew  + (size_t)(o0 + srow) * IN_F + g);
    bv  = *(const float4*)(basew  + (size_t)(o0 + srow) * IN_F + g);
  }

  for (int kc = 0; kc < NCH; ++kc) {
    if (kc) __syncthreads();          // prev-chunk readers done
    // ---------- transform prefetched regs -> LDS ----------
    {
      float4 sx0, sx1;
      sx0.x = fsilu(xv0.x); sx0.y = fsilu(xv0.y); sx0.z = fsilu(xv0.z); sx0.w = fsilu(xv0.w);
      sx1.x = fsilu(xv1.x); sx1.y = fsilu(xv1.y); sx1.z = fsilu(xv1.z); sx1.w = fsilu(xv1.w);
      *(float4*)(lx  + lofs) = xv0;
      *(float4*)(lsx + lofs) = sx0;
      *(float4*)(lx  + lofs + 64 * PITCH) = xv1;
      *(float4*)(lsx + lofs + 64 * PITCH) = sx1;

      float4 av, mv, nv;
      {
        float a2, a2t;
        a2 = C2f * frcp(sv.x * sv.x); a2t = a2 * tv.x;
        av.x = a2; mv.x = -2.f * a2t; nv.x = fmaf(a2t, tv.x, NC2f);
        a2 = C2f * frcp(sv.y * sv.y); a2t = a2 * tv.y;
        av.y = a2; mv.y = -2.f * a2t; nv.y = fmaf(a2t, tv.y, NC2f);
        a2 = C2f * frcp(sv.z * sv.z); a2t = a2 * tv.z;
        av.z = a2; mv.z = -2.f * a2t; nv.z = fmaf(a2t, tv.z, NC2f);
        a2 = C2f * frcp(sv.w * sv.w); a2t = a2 * tv.w;
        av.w = a2; mv.w = -2.f * a2t; nv.w = fmaf(a2t, tv.w, NC2f);
      }
      *(float4*)(la + lofs) = av;
      *(float4*)(lm + lofs) = mv;
      *(float4*)(ln + lofs) = nv;

      float4 qv;
      qv.x = wv.x * RQf; qv.y = wv.y * RQf; qv.z = wv.z * RQf; qv.w = wv.w * RQf;
      *(float4*)(lq + lofs) = qv;
      *(float4*)(lb + lofs) = bv;
    }
    __syncthreads();                  // chunk kc ready in LDS

    // ---------- issue next chunk's global loads (latency hides under compute)
    if (kc + 1 < NCH) {
      const int g = k0 + (kc + 1) * IT + sc4;
      xv0 = *(const float4*)(x      + (size_t)(b0 + srow)      * IN_F + g);
      xv1 = *(const float4*)(x      + (size_t)(b0 + srow + 64) * IN_F + g);
      sv  = *(const float4*)(scale  + (size_t)(o0 + srow) * IN_F + g);
      tv  = *(const float4*)(transl + (size_t)(o0 + srow) * IN_F + g);
      wv  = *(const float4*)(wavew  + (size_t)(o0 + srow) * IN_F + g);
      bv  = *(const float4*)(basew  + (size_t)(o0 + srow) * IN_F + g);
    }

    // ---------- compute: 8x4 outputs/thread ----------
    for (int ii = 0; ii < IT; ii += 4) {
      float4 xr[8], sr[8], x2[8];
#pragma unroll
      for (int r = 0; r < 8; ++r) {
        const int row = (tb + 16 * r) * PITCH + ii;
        xr[r] = *(const float4*)(lx + row);
        sr[r] = *(const float4*)(lsx + row);
        x2[r].x = xr[r].x * xr[r].x;
        x2[r].y = xr[r].y * xr[r].y;
        x2[r].z = xr[r].z * xr[r].z;
        x2[r].w = xr[r].w * xr[r].w;
      }
#pragma unroll
      for (int c = 0; c < 4; ++c) {
        const int orow = (to + 16 * c) * PITCH + ii;
        float4 A = *(const float4*)(la + orow);
        float4 M = *(const float4*)(lm + orow);
        float4 N = *(const float4*)(ln + orow);
        float4 Q = *(const float4*)(lq + orow);
        float4 B = *(const float4*)(lb + orow);
        v2f Al = {A.x, A.y}, Ah = {A.z, A.w};
        v2f Ml = {M.x, M.y}, Mh = {M.z, M.w};
        v2f Nl = {N.x, N.y}, Nh = {N.z, N.w};
        v2f Ql = {Q.x, Q.y}, Qh = {Q.z, Q.w};
        v2f Bl = {B.x, B.y}, Bh = {B.z, B.w};
#pragma unroll
        for (int r = 0; r < 8; ++r) {
          v2f xl  = {xr[r].x, xr[r].y}, xh  = {xr[r].z, xr[r].w};
          v2f x2l = {x2[r].x, x2[r].y}, x2h = {x2[r].z, x2[r].w};
          v2f sl  = {sr[r].x, sr[r].y}, sh  = {sr[r].z, sr[r].w};
          v2f p, e, gg;
          p = pkfma(Al, x2l, pkfma(Ml, xl, Nl));
          e.x = fexp2(p.x); e.y = fexp2(p.y);
          gg = p * Ql;
          acc[r][c] = pkfma(gg, e, acc[r][c]);
          acc[r][c] = pkfma(sl, Bl, acc[r][c]);
          p = pkfma(Ah, x2h, pkfma(Mh, xh, Nh));
          e.x = fexp2(p.x); e.y = fexp2(p.y);
          gg = p * Qh;
          acc[r][c] = pkfma(gg, e, acc[r][c]);
          acc[r][c] = pkfma(sh, Bh, acc[r][c]);
        }
      }
    }
  }

  // ---------- epilogue ----------
#pragma unroll
  for (int r = 0; r < 8; ++r) {
    const int br = b0 + tb + 16 * r;
#pragma unroll
    for (int c = 0; c < 4; ++c) {
      const int oc = o0 + to + 16 * c;
      float res = acc[r][c].x + acc[r][c].y;
      if (use_ws) {
        partial[(size_t)ks * BO + (size_t)br * OUT_F + oc] = res;
      } else {
        if (ks == 0) res += bias[oc];
        atomicAdd(out + (size_t)br * OUT_F + oc, res);
      }
    }
  }
}

__global__ __launch_bounds__(256)
void wkan_reduce(const float* __restrict__ partial, const float* __restrict__ bias,
                 float* __restrict__ out)
{
  const int i4 = (blockIdx.x * 256 + threadIdx.x) * 4;
  float4 r = *(const float4*)(bias + (i4 & (OUT_F - 1)));
#pragma unroll
  for (int k = 0; k < KS; ++k) {
    float4 a = *(const float4*)(partial + (size_t)k * BO + i4);
    r.x += a.x; r.y += a.y; r.z += a.z; r.w += a.w;
  }
  *(float4*)(out + i4) = r;
}

extern "C" void kernel_launch(void* const* d_in, const int* in_sizes, int n_in,
                              void* d_out, int out_size, void* d_ws, size_t ws_size,
                              hipStream_t stream) {
  const float* x  = (const float*)d_in[0];
  const float* bw = (const float*)d_in[1];
  const float* ww = (const float*)d_in[2];
  const float* sc = (const float*)d_in[3];
  const float* tr = (const float*)d_in[4];
  const float* bi = (const float*)d_in[5];
  float* out = (float*)d_out;

  const int use_ws = ws_size >= (size_t)KS * BO * sizeof(float) ? 1 : 0;
  if (!use_ws) {
    hipMemsetAsync(d_out, 0, (size_t)out_size * sizeof(float), stream);
  }
  dim3 grid(BATCH / BT, OUT_F / OT, KS);  // 8 x 8 x 8 = 512 blocks, 2/CU
  wkan_main<<<grid, dim3(256), 0, stream>>>(x, bw, ww, sc, tr, bi,
                                            (float*)d_ws, out, use_ws);
  if (use_ws) {
    wkan_reduce<<<dim3(BO / 1024), dim3(256), 0, stream>>>((const float*)d_ws, bi, out);
  }
}

// Round 3
// 111.107 us; speedup vs baseline: 1.0477x; 1.0335x over previous
//
#include <hip/hip_runtime.h>

// out[b,o] = sum_i silu(x)*BW + ((xs^2-1)*exp(-xs^2/2))*WW + bias,  xs=(x-T)/S
// ROUND 9: move the base branch (silu(x)@BW^T GEMM) off the VALU onto the
// matrix pipe via v_mfma_f32_16x16x16_f16.  Evidence: VALU busy-time is a
// constant ~33us at BOTH 2 and 4 waves/SIMD (R6 vs R8) -> instruction-issue
// floor, not latency.  pk-f32 ops are 4cyc/wave64 (157TF peak, packed does
// not double f32), v_exp quarter-rate ~8cyc: body = 10pk*4 + 4exp*8 = 72cyc
// per 4 contributions == measured busy.  Removing the base fma (1 of 5 pk)
// + its LDS reads (12 of 36/ii) + routing the GEMM to the idle MFMA pipe is
// the only instruction-count lever that doesn't touch wavelet accuracy.
//   - silu(x), basew staged as f16 tiles (HP=20 f16 pitch, conflict-free b64)
//   - base acc in f32 fragments over all 4 chunks; merged via LDS in epilogue
//   - MFMA layouts (AMD matrix calc, CDNA): A: m=l&15,k=(l>>4)*4+i;
//     B: n=l&15,k=(l>>4)*4+i;  D: n=l&15,m=(l>>4)*4+i
// Wavelet math unchanged (verified since round 2):
//   a2 = C2/s^2, m1 = -2*a2*t, m2' = a2*t^2 - C2, q = w * 2^C2 / C2
//   p = a2*x^2 + m1*x + m2';  contribution = p * q * 2^p,  C2 = -0.5*log2(e)

constexpr int IN_F  = 512;
constexpr int OUT_F = 512;
constexpr int BATCH = 1024;
constexpr int BT = 128, OT = 64;    // block tile
constexpr int KS = 8;               // k-split -> grid 8x8x8 = 512 blocks
constexpr int KR = IN_F / KS;       // 64 k per block
constexpr int IT = 16;              // k chunk in LDS
constexpr int PITCH = IT + 4;       // f32 rows: 16B-aligned, 2-way banks (free)
constexpr int HP = IT + 4;          // f16 rows: 40B stride -> conflict-free b64
constexpr int LP = OT + 1;          // epilogue merge pitch
constexpr int NCH = KR / IT;        // 4 chunks
constexpr int BO  = BATCH * OUT_F;  // 524288

#define LOG2E 1.44269504088897f
#define C2f   (-0.72134752044448f)
#define NC2f  ( 0.72134752044448f)
#define RQf   (-0.84083003f)   /* 2^C2 / C2 = e^{-1/2}/C2 */

typedef float v2f   __attribute__((ext_vector_type(2)));
typedef float f32x4 __attribute__((ext_vector_type(4)));
typedef _Float16 half4 __attribute__((ext_vector_type(4)));

__device__ __forceinline__ float fexp2(float v) { return __builtin_amdgcn_exp2f(v); }
__device__ __forceinline__ float frcp(float v)  { return __builtin_amdgcn_rcpf(v); }
__device__ __forceinline__ v2f pkfma(v2f a, v2f b, v2f c) {
  return __builtin_elementwise_fma(a, b, c);
}
__device__ __forceinline__ float fsilu(float v) {
  return v * frcp(1.f + fexp2(v * -LOG2E));
}

__global__ __launch_bounds__(256, 2)
void wkan_main(const float* __restrict__ x, const float* __restrict__ basew,
               const float* __restrict__ wavew, const float* __restrict__ scale,
               const float* __restrict__ transl, const float* __restrict__ bias,
               float* __restrict__ partial, float* __restrict__ out, int use_ws)
{
  __shared__ float lx [BT * PITCH];     // 10240 B  (x, f32)
  __shared__ float la [OT * PITCH];     //  5120 B each
  __shared__ float lm [OT * PITCH];
  __shared__ float ln [OT * PITCH];
  __shared__ float lq [OT * PITCH];
  __shared__ _Float16 hx [BT * HP];     //  5120 B  (silu(x), f16, MFMA A)
  __shared__ _Float16 hb [OT * HP];     //  2560 B  (basew, f16, MFMA B)
  __shared__ float lout[BT * LP];       // 33280 B  (epilogue merge)
                                        // total 71680 B -> 2 blocks/CU

  const int tid = threadIdx.x;
  const int b0 = blockIdx.x * BT;
  const int o0 = blockIdx.y * OT;
  const int ks = blockIdx.z;
  const int k0 = ks * KR;

  const int srow = tid >> 2;        // 0..63 staging row
  const int sc4  = (tid & 3) * 4;   // 0,4,8,12
  const int lofs = srow * PITCH + sc4;
  const int hofs = srow * HP + sc4;

  const int to = tid & 15;          // output col group (cols to + 16c)
  const int tb = tid >> 4;          // output row group 0..15 (rows tb + 16r)

  const int lane = tid & 63;
  const int wid  = tid >> 6;        // wave 0..3
  const int frow = lane & 15;       // m/n within MFMA tile
  const int kgrp = (lane >> 4) * 4; // k group within chunk

  v2f zz; zz.x = 0.f; zz.y = 0.f;
  v2f acc[8][4];
#pragma unroll
  for (int r = 0; r < 8; ++r)
#pragma unroll
    for (int c = 0; c < 4; ++c) acc[r][c] = zz;

  f32x4 accb[2][4];                 // base-GEMM fragments: 2 m-tiles x 4 n-tiles
#pragma unroll
  for (int mt = 0; mt < 2; ++mt)
#pragma unroll
    for (int nt = 0; nt < 4; ++nt) accb[mt][nt] = (f32x4)0.f;

  // prefetch registers (T14: live across the compute phase)
  float4 xv0, xv1, sv, tv, wv, bv;
  {
    const int g = k0 + sc4;
    xv0 = *(const float4*)(x      + (size_t)(b0 + srow)      * IN_F + g);
    xv1 = *(const float4*)(x      + (size_t)(b0 + srow + 64) * IN_F + g);
    sv  = *(const float4*)(scale  + (size_t)(o0 + srow) * IN_F + g);
    tv  = *(const float4*)(transl + (size_t)(o0 + srow) * IN_F + g);
    wv  = *(const float4*)(wavew  + (size_t)(o0 + srow) * IN_F + g);
    bv  = *(const float4*)(basew  + (size_t)(o0 + srow) * IN_F + g);
  }

  for (int kc = 0; kc < NCH; ++kc) {
    if (kc) __syncthreads();          // prev-chunk readers done
    // ---------- transform prefetched regs -> LDS ----------
    {
      float4 sx0, sx1;
      sx0.x = fsilu(xv0.x); sx0.y = fsilu(xv0.y); sx0.z = fsilu(xv0.z); sx0.w = fsilu(xv0.w);
      sx1.x = fsilu(xv1.x); sx1.y = fsilu(xv1.y); sx1.z = fsilu(xv1.z); sx1.w = fsilu(xv1.w);
      *(float4*)(lx + lofs) = xv0;
      *(float4*)(lx + lofs + 64 * PITCH) = xv1;
      half4 h0, h1;
      h0[0] = (_Float16)sx0.x; h0[1] = (_Float16)sx0.y;
      h0[2] = (_Float16)sx0.z; h0[3] = (_Float16)sx0.w;
      h1[0] = (_Float16)sx1.x; h1[1] = (_Float16)sx1.y;
      h1[2] = (_Float16)sx1.z; h1[3] = (_Float16)sx1.w;
      *(half4*)(hx + hofs) = h0;
      *(half4*)(hx + hofs + 64 * HP) = h1;

      float4 av, mv, nv;
      {
        float a2, a2t;
        a2 = C2f * frcp(sv.x * sv.x); a2t = a2 * tv.x;
        av.x = a2; mv.x = -2.f * a2t; nv.x = fmaf(a2t, tv.x, NC2f);
        a2 = C2f * frcp(sv.y * sv.y); a2t = a2 * tv.y;
        av.y = a2; mv.y = -2.f * a2t; nv.y = fmaf(a2t, tv.y, NC2f);
        a2 = C2f * frcp(sv.z * sv.z); a2t = a2 * tv.z;
        av.z = a2; mv.z = -2.f * a2t; nv.z = fmaf(a2t, tv.z, NC2f);
        a2 = C2f * frcp(sv.w * sv.w); a2t = a2 * tv.w;
        av.w = a2; mv.w = -2.f * a2t; nv.w = fmaf(a2t, tv.w, NC2f);
      }
      *(float4*)(la + lofs) = av;
      *(float4*)(lm + lofs) = mv;
      *(float4*)(ln + lofs) = nv;

      float4 qv;
      qv.x = wv.x * RQf; qv.y = wv.y * RQf; qv.z = wv.z * RQf; qv.w = wv.w * RQf;
      *(float4*)(lq + lofs) = qv;

      half4 hbv;
      hbv[0] = (_Float16)bv.x; hbv[1] = (_Float16)bv.y;
      hbv[2] = (_Float16)bv.z; hbv[3] = (_Float16)bv.w;
      *(half4*)(hb + hofs) = hbv;
    }
    __syncthreads();                  // chunk kc ready in LDS

    // ---------- issue next chunk's global loads (hide under compute) -------
    if (kc + 1 < NCH) {
      const int g = k0 + (kc + 1) * IT + sc4;
      xv0 = *(const float4*)(x      + (size_t)(b0 + srow)      * IN_F + g);
      xv1 = *(const float4*)(x      + (size_t)(b0 + srow + 64) * IN_F + g);
      sv  = *(const float4*)(scale  + (size_t)(o0 + srow) * IN_F + g);
      tv  = *(const float4*)(transl + (size_t)(o0 + srow) * IN_F + g);
      wv  = *(const float4*)(wavew  + (size_t)(o0 + srow) * IN_F + g);
      bv  = *(const float4*)(basew  + (size_t)(o0 + srow) * IN_F + g);
    }

    // ---------- base branch: 8 MFMA on the matrix pipe ----------
    {
      half4 af0 = *(const half4*)(hx + (wid * 32 +      frow) * HP + kgrp);
      half4 af1 = *(const half4*)(hx + (wid * 32 + 16 + frow) * HP + kgrp);
#pragma unroll
      for (int nt = 0; nt < 4; ++nt) {
        half4 bf = *(const half4*)(hb + (nt * 16 + frow) * HP + kgrp);
        accb[0][nt] = __builtin_amdgcn_mfma_f32_16x16x16f16(af0, bf, accb[0][nt], 0, 0, 0);
        accb[1][nt] = __builtin_amdgcn_mfma_f32_16x16x16f16(af1, bf, accb[1][nt], 0, 0, 0);
      }
    }

    // ---------- wavelet: 8x4 outputs/thread on the VALU ----------
    for (int ii = 0; ii < IT; ii += 4) {
      float4 xr[8], x2[8];
#pragma unroll
      for (int r = 0; r < 8; ++r) {
        const int row = (tb + 16 * r) * PITCH + ii;
        xr[r] = *(const float4*)(lx + row);
        x2[r].x = xr[r].x * xr[r].x;
        x2[r].y = xr[r].y * xr[r].y;
        x2[r].z = xr[r].z * xr[r].z;
        x2[r].w = xr[r].w * xr[r].w;
      }
#pragma unroll
      for (int c = 0; c < 4; ++c) {
        const int orow = (to + 16 * c) * PITCH + ii;
        float4 A = *(const float4*)(la + orow);
        float4 M = *(const float4*)(lm + orow);
        float4 N = *(const float4*)(ln + orow);
        float4 Q = *(const float4*)(lq + orow);
        v2f Al = {A.x, A.y}, Ah = {A.z, A.w};
        v2f Ml = {M.x, M.y}, Mh = {M.z, M.w};
        v2f Nl = {N.x, N.y}, Nh = {N.z, N.w};
        v2f Ql = {Q.x, Q.y}, Qh = {Q.z, Q.w};
#pragma unroll
        for (int r = 0; r < 8; ++r) {
          v2f xl  = {xr[r].x, xr[r].y}, xh  = {xr[r].z, xr[r].w};
          v2f x2l = {x2[r].x, x2[r].y}, x2h = {x2[r].z, x2[r].w};
          v2f p, e, gg;
          p = pkfma(Al, x2l, pkfma(Ml, xl, Nl));
          e.x = fexp2(p.x); e.y = fexp2(p.y);
          gg = p * Ql;
          acc[r][c] = pkfma(gg, e, acc[r][c]);
          p = pkfma(Ah, x2h, pkfma(Mh, xh, Nh));
          e.x = fexp2(p.x); e.y = fexp2(p.y);
          gg = p * Qh;
          acc[r][c] = pkfma(gg, e, acc[r][c]);
        }
      }
    }
  }

  // ---------- epilogue: merge base fragments with wavelet acc ----------
  // D layout: n = lane&15, m = (lane>>4)*4 + i   (within each 16x16 tile)
#pragma unroll
  for (int mt = 0; mt < 2; ++mt)
#pragma unroll
    for (int nt = 0; nt < 4; ++nt)
#pragma unroll
      for (int i = 0; i < 4; ++i)
        lout[(wid * 32 + mt * 16 + (lane >> 4) * 4 + i) * LP + nt * 16 + frow]
            = accb[mt][nt][i];
  __syncthreads();

#pragma unroll
  for (int r = 0; r < 8; ++r) {
    const int br = b0 + tb + 16 * r;
#pragma unroll
    for (int c = 0; c < 4; ++c) {
      const int oc = o0 + to + 16 * c;
      float res = acc[r][c].x + acc[r][c].y
                + lout[(tb + 16 * r) * LP + to + 16 * c];
      if (use_ws) {
        partial[(size_t)ks * BO + (size_t)br * OUT_F + oc] = res;
      } else {
        if (ks == 0) res += bias[oc];
        atomicAdd(out + (size_t)br * OUT_F + oc, res);
      }
    }
  }
}

__global__ __launch_bounds__(256)
void wkan_reduce(const float* __restrict__ partial, const float* __restrict__ bias,
                 float* __restrict__ out)
{
  const int i4 = (blockIdx.x * 256 + threadIdx.x) * 4;
  float4 r = *(const float4*)(bias + (i4 & (OUT_F - 1)));
#pragma unroll
  for (int k = 0; k < KS; ++k) {
    float4 a = *(const float4*)(partial + (size_t)k * BO + i4);
    r.x += a.x; r.y += a.y; r.z += a.z; r.w += a.w;
  }
  *(float4*)(out + i4) = r;
}

extern "C" void kernel_launch(void* const* d_in, const int* in_sizes, int n_in,
                              void* d_out, int out_size, void* d_ws, size_t ws_size,
                              hipStream_t stream) {
  const float* x  = (const float*)d_in[0];
  const float* bw = (const float*)d_in[1];
  const float* ww = (const float*)d_in[2];
  const float* sc = (const float*)d_in[3];
  const float* tr = (const float*)d_in[4];
  const float* bi = (const float*)d_in[5];
  float* out = (float*)d_out;

  const int use_ws = ws_size >= (size_t)KS * BO * sizeof(float) ? 1 : 0;
  if (!use_ws) {
    hipMemsetAsync(d_out, 0, (size_t)out_size * sizeof(float), stream);
  }
  dim3 grid(BATCH / BT, OUT_F / OT, KS);  // 8 x 8 x 8 = 512 blocks, 2/CU
  wkan_main<<<grid, dim3(256), 0, stream>>>(x, bw, ww, sc, tr, bi,
                                            (float*)d_ws, out, use_ws);
  if (use_ws) {
    wkan_reduce<<<dim3(BO / 1024), dim3(256), 0, stream>>>((const float*)d_ws, bi, out);
  }
}